// Round 6
// baseline (5289.867 us; speedup 1.0000x reference)
//
#include <hip/hip_runtime.h>
#include <math.h>

#define TB 16
#define TT 8192
#define TM 128
#define ED 512     // EMBED_DIM
#define QD 256     // QUANT_DIM
#define QN 1024    // QUANT_N
#define NTOK 65536

// ---------------- kernel 1: codebook l2-normalize -> quad-interleaved cbq ----------------
// cbq layout: [QD/4 quads][QN codes][4 floats]; lane's float4 IS its k-quad.
__global__ __launch_bounds__(64) void k_cbnorm(const float* __restrict__ cb,
                                               float4* __restrict__ cbq) {
    int k = blockIdx.x;
    int lane = threadIdx.x;               // 64 lanes, one k-quad each
    float4 v = ((const float4*)(cb + (size_t)k * QD))[lane];
    float ss = v.x*v.x + v.y*v.y + v.z*v.z + v.w*v.w;
    #pragma unroll
    for (int off = 32; off > 0; off >>= 1) ss += __shfl_down(ss, off);
    ss = __shfl(ss, 0);
    float inv = 1.0f / fmaxf(sqrtf(ss), 1e-12f);
    float4 o; o.x = v.x*inv; o.y = v.y*inv; o.z = v.z*inv; o.w = v.w*inv;
    cbq[(size_t)lane * QN + k] = o;
}

// ---------------- kernel 2: precompute M2 = [Wt@P | Wt@W] (quad-interleaved), wsum, p1 ----
__global__ __launch_bounds__(256) void k_prep(const float* __restrict__ convw,
                                              const float* __restrict__ proj,
                                              float4* __restrict__ m2q,
                                              float* __restrict__ wsum,
                                              float* __restrict__ p1) {
    int col = blockIdx.x;
    int t = threadIdx.x;
    if (col < 512) {
        __shared__ float colv[512];
        const float* src = (col < 256) ? (proj + col) : (convw + (col - 256));
        colv[t]       = src[(size_t)t * 256];
        colv[t + 256] = src[(size_t)(t + 256) * 256];
        __syncthreads();
        float acc = 0.f;
        for (int d = 0; d < 512; ++d)
            acc += convw[d * 256 + t] * colv[d];
        float* dst = (float*)&m2q[(size_t)(t >> 2) * 512 + col];
        dst[t & 3] = acc;
    } else if (col == 512) {
        float s = 0.f;
        for (int d = 0; d < 512; ++d) s += convw[d * 256 + t];
        wsum[t] = s;
    } else {
        float s = 0.f;
        for (int d = 0; d < 512; ++d) s += proj[d * 256 + t];
        p1[t] = s;
    }
}

// ---------------- kernel 3: fully fused patch-GEMM + LN + codebook GEMM + argmax ----------
// ATOK=32 tokens/block (grid exactly 2048). Unified 96-stage pipeline:
// stages 0..31 = m2q K-slices (GEMM1: v = patch @ [M|G]); LN epilogue writes t
// back into Ts; stages 32..95 = cbq K-slices x 2 code-chunks (GEMM2 + argmax).
// Register-prefetch of stage s+1 is issued BEFORE compute of stage s.
#define ATOK 32
#define TSTR2 260

__global__ __launch_bounds__(256, 3) void k_fused(const float* __restrict__ fbank,
                                                  const float4* __restrict__ m2q,
                                                  const float4* __restrict__ cbq,
                                                  const float* __restrict__ wsum,
                                                  const float* __restrict__ p1,
                                                  int* __restrict__ out) {
    __shared__ float  Ts[ATOK * TSTR2];   // 33.3 KB: patches, then t
    __shared__ float4 Cs[2][512];         // 16 KB staging
    __shared__ float  wsS[256], p1S[256];

    int tid = threadIdx.x;
    int n0 = blockIdx.x * ATOK;

    wsS[tid] = wsum[tid];
    p1S[tid] = p1[tid];

    // ---- stage 32 patches: 512 segments of 16 floats; 2 per thread ----
    #pragma unroll
    for (int i = 0; i < 2; ++i) {
        int s = tid + 256 * i;           // 0..511
        int j = s >> 4, ph = s & 15;
        int n = n0 + j;
        int b = n >> 12, r = n & 4095, h = r >> 3, w = r & 7;
        const float4* src = (const float4*)(fbank + ((size_t)(b * TT + h * 16 + ph)) * TM + w * 16);
        float4* dst = (float4*)&Ts[j * TSTR2 + ph * 16];
        #pragma unroll
        for (int c = 0; c < 4; ++c) dst[c] = src[c];
    }

    int tg = tid >> 5;       // 0..7: tokens {tg + 8u, u=0..3}
    int cg = tid & 31;       // cols {cg + 32j, j=0..15}
    int qloc = tid >> 7;     // staging k-quad
    int cidx = tid & 127;    // staging col base

    float acc[4][16];
    #pragma unroll
    for (int u = 0; u < 4; ++u)
        #pragma unroll
        for (int j = 0; j < 16; ++j) acc[u][j] = 0.f;

    float4 st[4];
    #pragma unroll
    for (int i = 0; i < 4; ++i)          // preload stage 0 (m2q kc=0)
        st[i] = m2q[(size_t)qloc * 512 + cidx + 128 * i];

    // ================= GEMM1: stages 0..31 =================
    for (int kc = 0; kc < 32; ++kc) {
        __syncthreads();   // prior compute done with Cs (kc=0: publishes Ts/wsS/p1S)
        #pragma unroll
        for (int i = 0; i < 4; ++i)
            Cs[qloc][cidx + 128 * i] = st[i];
        __syncthreads();

        // prefetch next stage BEFORE compute (latency hidden under FMAs)
        if (kc < 31) {
            #pragma unroll
            for (int i = 0; i < 4; ++i)
                st[i] = m2q[(size_t)((kc + 1) * 2 + qloc) * 512 + cidx + 128 * i];
        } else {
            #pragma unroll
            for (int i = 0; i < 4; ++i)  // first cbq stage (chunk 0, kc2=0)
                st[i] = cbq[(size_t)qloc * QN + cidx + 128 * i];
        }

        #pragma unroll
        for (int kq = 0; kq < 2; ++kq) {
            float4 tv[4];
            #pragma unroll
            for (int u = 0; u < 4; ++u)       // wave-broadcast reads
                tv[u] = *(const float4*)&Ts[(tg + 8*u) * TSTR2 + kc * 8 + kq * 4];
            #pragma unroll
            for (int j = 0; j < 16; ++j) {
                float4 cv = Cs[kq][cg + 32*j]; // lane-contiguous b128 reads
                #pragma unroll
                for (int u = 0; u < 4; ++u) {
                    acc[u][j] += tv[u].x * cv.x;
                    acc[u][j] += tv[u].y * cv.y;
                    acc[u][j] += tv[u].z * cv.z;
                    acc[u][j] += tv[u].w * cv.w;
                }
            }
        }
    }

    // ---- LN epilogue: mu / sumsq via half-wave reduction ----
    float part_sq[4], part_mu[4];
    #pragma unroll
    for (int u = 0; u < 4; ++u) {
        const float* trow = &Ts[(tg + 8*u) * TSTR2];
        float sq = 0.f;
        #pragma unroll
        for (int j = 8; j < 16; ++j)          // G-cols: 32*(j-8)+cg
            sq += acc[u][j] * trow[32 * (j - 8) + cg];
        float pm = 0.f;
        #pragma unroll
        for (int z = 0; z < 8; ++z) {
            int k = cg + 32 * z;
            pm += trow[k] * wsS[k];
        }
        part_sq[u] = sq; part_mu[u] = pm;
    }
    #pragma unroll
    for (int off = 16; off > 0; off >>= 1) {
        #pragma unroll
        for (int u = 0; u < 4; ++u) {
            part_sq[u] += __shfl_down(part_sq[u], off);
            part_mu[u] += __shfl_down(part_mu[u], off);
        }
    }
    int base = (tid & 63) & 32;
    #pragma unroll
    for (int u = 0; u < 4; ++u) {
        float sq = __shfl(part_sq[u], base);
        float pm = __shfl(part_mu[u], base);
        float m = pm * (1.0f / 512.0f);
        float v = sq * (1.0f / 512.0f) - m * m;
        float rs = rsqrtf(v + 1e-5f);         // positive scale: argmax-neutral
        // write t into Ts (cols == cg mod 32: this thread read exactly these
        // cols of its rows above -> no barrier needed before overwrite; the
        // staging barrier below publishes t to all threads)
        #pragma unroll
        for (int j = 0; j < 8; ++j) {
            int q = 32 * j + cg;
            Ts[(tg + 8*u) * TSTR2 + q] = rs * (acc[u][j] - m * p1S[q]);
        }
    }

    // ================= GEMM2 + argmax: stages 32..95 =================
    float best[4]; int bidx[4];
    #pragma unroll
    for (int u = 0; u < 4; ++u) { best[u] = -3.4e38f; bidx[u] = 0; }

    for (int chunk = 0; chunk < 2; ++chunk) {
        #pragma unroll
        for (int u = 0; u < 4; ++u)
            #pragma unroll
            for (int j = 0; j < 16; ++j) acc[u][j] = 0.f;

        for (int kc = 0; kc < 32; ++kc) {
            __syncthreads();   // (first pass: publishes t-writes)
            #pragma unroll
            for (int i = 0; i < 4; ++i)
                Cs[qloc][cidx + 128 * i] = st[i];
            __syncthreads();

            // prefetch next cbq stage
            int sNext = chunk * 32 + kc + 1;   // 1..64
            if (sNext < 64) {
                int ch2 = sNext >> 5, kc2 = sNext & 31;
                #pragma unroll
                for (int i = 0; i < 4; ++i)
                    st[i] = cbq[(size_t)(kc2 * 2 + qloc) * QN + ch2 * 512 + cidx + 128 * i];
            }

            #pragma unroll
            for (int kq = 0; kq < 2; ++kq) {
                float4 tv[4];
                #pragma unroll
                for (int u = 0; u < 4; ++u)
                    tv[u] = *(const float4*)&Ts[(tg + 8*u) * TSTR2 + kc * 8 + kq * 4];
                #pragma unroll
                for (int j = 0; j < 16; ++j) {
                    float4 cv = Cs[kq][cg + 32*j];
                    #pragma unroll
                    for (int u = 0; u < 4; ++u) {
                        acc[u][j] += tv[u].x * cv.x;
                        acc[u][j] += tv[u].y * cv.y;
                        acc[u][j] += tv[u].z * cv.z;
                        acc[u][j] += tv[u].w * cv.w;
                    }
                }
            }
        }
        // fold chunk (ascending code index, strict > : first-max tie-break)
        #pragma unroll
        for (int j = 0; j < 16; ++j) {
            int code = chunk * 512 + 32 * j + cg;
            #pragma unroll
            for (int u = 0; u < 4; ++u) {
                if (acc[u][j] > best[u]) { best[u] = acc[u][j]; bidx[u] = code; }
            }
        }
    }

    // ---- reduce across the 32 code-lanes of each half-wave ----
    #pragma unroll
    for (int off = 16; off > 0; off >>= 1) {
        #pragma unroll
        for (int u = 0; u < 4; ++u) {
            float ov = __shfl_down(best[u], off);
            int   oi = __shfl_down(bidx[u], off);
            if (ov > best[u] || (ov == best[u] && oi < bidx[u])) {
                best[u] = ov; bidx[u] = oi;
            }
        }
    }
    if (cg == 0) {
        #pragma unroll
        for (int u = 0; u < 4; ++u) out[n0 + tg + 8*u] = bidx[u];
    }
}

extern "C" void kernel_launch(void* const* d_in, const int* in_sizes, int n_in,
                              void* d_out, int out_size, void* d_ws, size_t ws_size,
                              hipStream_t stream) {
    const float* fbank = (const float*)d_in[0];   // 16 x 8192 x 128
    const float* convw = (const float*)d_in[1];   // 512 x 1 x 16 x 16 (= [512][256])
    const float* proj  = (const float*)d_in[2];   // 512 x 256
    const float* cbook = (const float*)d_in[3];   // 1024 x 256
    int* out = (int*)d_out;                       // 65536 int32

    char* ws = (char*)d_ws;
    float4* cbq  = (float4*)ws;                              // 1 MB
    float4* m2q  = (float4*)(ws + (1u << 20));               // 512 KB
    float*  wsum = (float*)(ws + (1u << 20) + (1u << 19));   // 1 KB
    float*  p1   = (float*)(ws + (1u << 20) + (1u << 19) + 4096);

    hipLaunchKernelGGL(k_cbnorm, dim3(QN),  dim3(64),  0, stream, cbook, cbq);
    hipLaunchKernelGGL(k_prep,   dim3(514), dim3(256), 0, stream, convw, proj, m2q, wsum, p1);
    hipLaunchKernelGGL(k_fused,  dim3(NTOK / ATOK), dim3(256), 0, stream,
                       fbank, m2q, cbq, wsum, p1, out);
}

// Round 7
// 1151.792 us; speedup vs baseline: 4.5927x; 4.5927x over previous
//
#include <hip/hip_runtime.h>
#include <math.h>

#define TB 16
#define TT 8192
#define TM 128
#define ED 512     // EMBED_DIM
#define QD 256     // QUANT_DIM
#define QN 1024    // QUANT_N
#define NTOK 65536

// ---------------- kernel 1: codebook l2-normalize -> quad-interleaved cbq ----------------
// cbq layout: [QD/4 quads][QN codes][4 floats]; lane's float4 IS its k-quad.
__global__ __launch_bounds__(64) void k_cbnorm(const float* __restrict__ cb,
                                               float4* __restrict__ cbq) {
    int k = blockIdx.x;
    int lane = threadIdx.x;               // 64 lanes, one k-quad each
    float4 v = ((const float4*)(cb + (size_t)k * QD))[lane];
    float ss = v.x*v.x + v.y*v.y + v.z*v.z + v.w*v.w;
    #pragma unroll
    for (int off = 32; off > 0; off >>= 1) ss += __shfl_down(ss, off);
    ss = __shfl(ss, 0);
    float inv = 1.0f / fmaxf(sqrtf(ss), 1e-12f);
    float4 o; o.x = v.x*inv; o.y = v.y*inv; o.z = v.z*inv; o.w = v.w*inv;
    cbq[(size_t)lane * QN + k] = o;
}

// ---------------- kernel 2: precompute M2 = [Wt@P | Wt@W] (quad-interleaved), wsum, p1 ----
__global__ __launch_bounds__(256) void k_prep(const float* __restrict__ convw,
                                              const float* __restrict__ proj,
                                              float4* __restrict__ m2q,
                                              float* __restrict__ wsum,
                                              float* __restrict__ p1) {
    int col = blockIdx.x;
    int t = threadIdx.x;
    if (col < 512) {
        __shared__ float colv[512];
        const float* src = (col < 256) ? (proj + col) : (convw + (col - 256));
        colv[t]       = src[(size_t)t * 256];
        colv[t + 256] = src[(size_t)(t + 256) * 256];
        __syncthreads();
        float acc = 0.f;
        for (int d = 0; d < 512; ++d)
            acc += convw[d * 256 + t] * colv[d];
        float* dst = (float*)&m2q[(size_t)(t >> 2) * 512 + col];
        dst[t & 3] = acc;
    } else if (col == 512) {
        float s = 0.f;
        for (int d = 0; d < 512; ++d) s += convw[d * 256 + t];
        wsum[t] = s;
    } else {
        float s = 0.f;
        for (int d = 0; d < 512; ++d) s += proj[d * 256 + t];
        p1[t] = s;
    }
}

// ---------------- kernel 3: fully fused patch-GEMM + LN + codebook GEMM + argmax ----------
// ATOK=32 tokens/block (grid exactly 2048). Unified 96-stage pipeline:
// stages 0..31 = m2q K-slices (GEMM1: v = patch @ [M|G]); LN epilogue writes t
// back into Ts; stages 32..95 = cbq K-slices x 2 code-chunks (GEMM2 + argmax).
// Register-prefetch of stage s+1 is issued BEFORE compute of stage s.
// __launch_bounds__(256,2): VGPR cap 128 (arg 3 capped at 84 -> massive scratch
// spill, 26 GB HBM traffic, round 6). Occupancy comes from LDS: 51.7 KB -> 3 blocks/CU.
#define ATOK 32
#define TSTR2 260

__global__ __launch_bounds__(256, 2) void k_fused(const float* __restrict__ fbank,
                                                  const float4* __restrict__ m2q,
                                                  const float4* __restrict__ cbq,
                                                  const float* __restrict__ wsum,
                                                  const float* __restrict__ p1,
                                                  int* __restrict__ out) {
    __shared__ float  Ts[ATOK * TSTR2];   // 33.3 KB: patches, then t
    __shared__ float4 Cs[2][512];         // 16 KB staging
    __shared__ float  wsS[256], p1S[256];

    int tid = threadIdx.x;
    int n0 = blockIdx.x * ATOK;

    wsS[tid] = wsum[tid];
    p1S[tid] = p1[tid];

    // ---- stage 32 patches: 512 segments of 16 floats; 2 per thread ----
    #pragma unroll
    for (int i = 0; i < 2; ++i) {
        int s = tid + 256 * i;           // 0..511
        int j = s >> 4, ph = s & 15;
        int n = n0 + j;
        int b = n >> 12, r = n & 4095, h = r >> 3, w = r & 7;
        const float4* src = (const float4*)(fbank + ((size_t)(b * TT + h * 16 + ph)) * TM + w * 16);
        float4* dst = (float4*)&Ts[j * TSTR2 + ph * 16];
        #pragma unroll
        for (int c = 0; c < 4; ++c) dst[c] = src[c];
    }

    int tg = tid >> 5;       // 0..7: tokens {tg + 8u, u=0..3}
    int cg = tid & 31;       // cols {cg + 32j, j=0..15}
    int qloc = tid >> 7;     // staging k-quad
    int cidx = tid & 127;    // staging col base

    float acc[4][16];
    #pragma unroll
    for (int u = 0; u < 4; ++u)
        #pragma unroll
        for (int j = 0; j < 16; ++j) acc[u][j] = 0.f;

    float4 st[4];
    #pragma unroll
    for (int i = 0; i < 4; ++i)          // preload stage 0 (m2q kc=0)
        st[i] = m2q[(size_t)qloc * 512 + cidx + 128 * i];

    // ================= GEMM1: stages 0..31 =================
    for (int kc = 0; kc < 32; ++kc) {
        __syncthreads();   // prior compute done with Cs (kc=0: publishes Ts/wsS/p1S)
        #pragma unroll
        for (int i = 0; i < 4; ++i)
            Cs[qloc][cidx + 128 * i] = st[i];
        __syncthreads();

        // prefetch next stage BEFORE compute (latency hidden under FMAs)
        if (kc < 31) {
            #pragma unroll
            for (int i = 0; i < 4; ++i)
                st[i] = m2q[(size_t)((kc + 1) * 2 + qloc) * 512 + cidx + 128 * i];
        } else {
            #pragma unroll
            for (int i = 0; i < 4; ++i)  // first cbq stage (chunk 0, kc2=0)
                st[i] = cbq[(size_t)qloc * QN + cidx + 128 * i];
        }

        #pragma unroll
        for (int kq = 0; kq < 2; ++kq) {
            float4 tv[4];
            #pragma unroll
            for (int u = 0; u < 4; ++u)       // wave-broadcast reads
                tv[u] = *(const float4*)&Ts[(tg + 8*u) * TSTR2 + kc * 8 + kq * 4];
            #pragma unroll
            for (int j = 0; j < 16; ++j) {
                float4 cv = Cs[kq][cg + 32*j]; // lane-contiguous b128 reads
                #pragma unroll
                for (int u = 0; u < 4; ++u) {
                    acc[u][j] += tv[u].x * cv.x;
                    acc[u][j] += tv[u].y * cv.y;
                    acc[u][j] += tv[u].z * cv.z;
                    acc[u][j] += tv[u].w * cv.w;
                }
            }
        }
    }

    // ---- LN epilogue: mu / sumsq via half-wave reduction ----
    float part_sq[4], part_mu[4];
    #pragma unroll
    for (int u = 0; u < 4; ++u) {
        const float* trow = &Ts[(tg + 8*u) * TSTR2];
        float sq = 0.f;
        #pragma unroll
        for (int j = 8; j < 16; ++j)          // G-cols: 32*(j-8)+cg
            sq += acc[u][j] * trow[32 * (j - 8) + cg];
        float pm = 0.f;
        #pragma unroll
        for (int z = 0; z < 8; ++z) {
            int k = cg + 32 * z;
            pm += trow[k] * wsS[k];
        }
        part_sq[u] = sq; part_mu[u] = pm;
    }
    #pragma unroll
    for (int off = 16; off > 0; off >>= 1) {
        #pragma unroll
        for (int u = 0; u < 4; ++u) {
            part_sq[u] += __shfl_down(part_sq[u], off);
            part_mu[u] += __shfl_down(part_mu[u], off);
        }
    }
    int base = (tid & 63) & 32;
    #pragma unroll
    for (int u = 0; u < 4; ++u) {
        float sq = __shfl(part_sq[u], base);
        float pm = __shfl(part_mu[u], base);
        float m = pm * (1.0f / 512.0f);
        float v = sq * (1.0f / 512.0f) - m * m;
        float rs = rsqrtf(v + 1e-5f);         // positive scale: argmax-neutral
        // write t into Ts (cols == cg mod 32: this thread read exactly these
        // cols of its rows above -> no barrier needed before overwrite; the
        // staging barrier below publishes t to all threads)
        #pragma unroll
        for (int j = 0; j < 8; ++j) {
            int q = 32 * j + cg;
            Ts[(tg + 8*u) * TSTR2 + q] = rs * (acc[u][j] - m * p1S[q]);
        }
    }

    // ================= GEMM2 + argmax: stages 32..95 =================
    float best[4]; int bidx[4];
    #pragma unroll
    for (int u = 0; u < 4; ++u) { best[u] = -3.4e38f; bidx[u] = 0; }

    for (int chunk = 0; chunk < 2; ++chunk) {
        #pragma unroll
        for (int u = 0; u < 4; ++u)
            #pragma unroll
            for (int j = 0; j < 16; ++j) acc[u][j] = 0.f;

        for (int kc = 0; kc < 32; ++kc) {
            __syncthreads();   // (first pass: publishes t-writes)
            #pragma unroll
            for (int i = 0; i < 4; ++i)
                Cs[qloc][cidx + 128 * i] = st[i];
            __syncthreads();

            // prefetch next cbq stage
            int sNext = chunk * 32 + kc + 1;   // 1..64
            if (sNext < 64) {
                int ch2 = sNext >> 5, kc2 = sNext & 31;
                #pragma unroll
                for (int i = 0; i < 4; ++i)
                    st[i] = cbq[(size_t)(kc2 * 2 + qloc) * QN + ch2 * 512 + cidx + 128 * i];
            }

            #pragma unroll
            for (int kq = 0; kq < 2; ++kq) {
                float4 tv[4];
                #pragma unroll
                for (int u = 0; u < 4; ++u)
                    tv[u] = *(const float4*)&Ts[(tg + 8*u) * TSTR2 + kc * 8 + kq * 4];
                #pragma unroll
                for (int j = 0; j < 16; ++j) {
                    float4 cv = Cs[kq][cg + 32*j];
                    #pragma unroll
                    for (int u = 0; u < 4; ++u) {
                        acc[u][j] += tv[u].x * cv.x;
                        acc[u][j] += tv[u].y * cv.y;
                        acc[u][j] += tv[u].z * cv.z;
                        acc[u][j] += tv[u].w * cv.w;
                    }
                }
            }
        }
        // fold chunk (ascending code index, strict > : first-max tie-break)
        #pragma unroll
        for (int j = 0; j < 16; ++j) {
            int code = chunk * 512 + 32 * j + cg;
            #pragma unroll
            for (int u = 0; u < 4; ++u) {
                if (acc[u][j] > best[u]) { best[u] = acc[u][j]; bidx[u] = code; }
            }
        }
    }

    // ---- reduce across the 32 code-lanes of each half-wave ----
    #pragma unroll
    for (int off = 16; off > 0; off >>= 1) {
        #pragma unroll
        for (int u = 0; u < 4; ++u) {
            float ov = __shfl_down(best[u], off);
            int   oi = __shfl_down(bidx[u], off);
            if (ov > best[u] || (ov == best[u] && oi < bidx[u])) {
                best[u] = ov; bidx[u] = oi;
            }
        }
    }
    if (cg == 0) {
        #pragma unroll
        for (int u = 0; u < 4; ++u) out[n0 + tg + 8*u] = bidx[u];
    }
}

extern "C" void kernel_launch(void* const* d_in, const int* in_sizes, int n_in,
                              void* d_out, int out_size, void* d_ws, size_t ws_size,
                              hipStream_t stream) {
    const float* fbank = (const float*)d_in[0];   // 16 x 8192 x 128
    const float* convw = (const float*)d_in[1];   // 512 x 1 x 16 x 16 (= [512][256])
    const float* proj  = (const float*)d_in[2];   // 512 x 256
    const float* cbook = (const float*)d_in[3];   // 1024 x 256
    int* out = (int*)d_out;                       // 65536 int32

    char* ws = (char*)d_ws;
    float4* cbq  = (float4*)ws;                              // 1 MB
    float4* m2q  = (float4*)(ws + (1u << 20));               // 512 KB
    float*  wsum = (float*)(ws + (1u << 20) + (1u << 19));   // 1 KB
    float*  p1   = (float*)(ws + (1u << 20) + (1u << 19) + 4096);

    hipLaunchKernelGGL(k_cbnorm, dim3(QN),  dim3(64),  0, stream, cbook, cbq);
    hipLaunchKernelGGL(k_prep,   dim3(514), dim3(256), 0, stream, convw, proj, m2q, wsum, p1);
    hipLaunchKernelGGL(k_fused,  dim3(NTOK / ATOK), dim3(256), 0, stream,
                       fbank, m2q, cbq, wsum, p1, out);
}

// Round 8
// 659.173 us; speedup vs baseline: 8.0250x; 1.7473x over previous
//
#include <hip/hip_runtime.h>
#include <math.h>

#define QD 256
#define QN 1024
#define NTOK 65536
#define TT 8192

typedef __bf16 bf16x8 __attribute__((ext_vector_type(8)));
typedef float  f32x16 __attribute__((ext_vector_type(16)));
typedef unsigned short ushort_t;
typedef unsigned short us8 __attribute__((ext_vector_type(8)));

// LDS byte offsets (k_mega), total 139264
#define PL 0          // bf16 planes [3][2 mt][16 kc][64 lane][16B] = 98304 (plane stride 32768)
#define DB 98304      // B dbuf [2][16 nt][64][16B] = 32768 ; reused as P32[32][257] f32 in LN
#define RV 131072     // redV [64][8] f32
#define RI 133120     // redI [64][8] i32
#define WS 135168     // wsS [256] f32
#define P1O 136192    // p1S [256] f32
#define MP 137216     // muP [32][8] f32
#define SP 138240     // sqP [32][4] f32
#define LM 138752     // lnMu [64]
#define LR 139008     // lnRs [64]
#define SMEM_TOTAL 139264

// exact 3-way bf16 split (truncation; x = h+m+l up to ~2^-25|x|)
__device__ __forceinline__ void split3(float x, ushort_t& h, ushort_t& m, ushort_t& l) {
    unsigned int xu = __float_as_uint(x);
    h = (ushort_t)(xu >> 16);
    float hf = __uint_as_float(xu & 0xFFFF0000u);
    float r1 = x - hf;                       // exact
    unsigned int r1u = __float_as_uint(r1);
    m = (ushort_t)(r1u >> 16);
    float mf = __uint_as_float(r1u & 0xFFFF0000u);
    float r2 = r1 - mf;                      // exact
    l = (ushort_t)(__float_as_uint(r2) >> 16);
}
__device__ __forceinline__ float rejoin(ushort_t h, ushort_t m, ushort_t l) {
    return __uint_as_float((unsigned)h << 16) + __uint_as_float((unsigned)m << 16)
         + __uint_as_float((unsigned)l << 16);
}
__device__ __forceinline__ f32x16 MF(bf16x8 a, bf16x8 b, f32x16 c) {
    return __builtin_amdgcn_mfma_f32_32x32x16_bf16(a, b, c, 0, 0, 0);
}
// segment -> plane pair (A,B): (0,0)(0,1)(1,0)(0,2)(1,1)(2,0)
__device__ __forceinline__ int paOf(int s) { return (s==2||s==4) ? 1 : ((s==5) ? 2 : 0); }
__device__ __forceinline__ int pbOf(int s) { return (s==3) ? 2 : ((s==1||s==4) ? 1 : 0); }

// ---------- k_cbnorm: l2-normalize codebook -> 3 bf16 planes in frag layout ----------
// cbp[p][kc 16][nt 32][lane 64][8]: element (code c, k): nt=c>>5, lane=((k>>3)&1)*32+(c&31), j=k&7
__global__ __launch_bounds__(64) void k_cbnorm(const float* __restrict__ cb,
                                               ushort_t* __restrict__ cbp) {
    int c = blockIdx.x, lane = threadIdx.x;
    float4 v = ((const float4*)(cb + (size_t)c * QD))[lane];
    float ss = v.x*v.x + v.y*v.y + v.z*v.z + v.w*v.w;
    #pragma unroll
    for (int off = 32; off > 0; off >>= 1) ss += __shfl_down(ss, off);
    ss = __shfl(ss, 0);
    float inv = 1.0f / fmaxf(sqrtf(ss), 1e-12f);
    float vals[4] = {v.x*inv, v.y*inv, v.z*inv, v.w*inv};
    #pragma unroll
    for (int i = 0; i < 4; ++i) {
        int k = 4*lane + i;
        ushort_t hb, mb, lb; split3(vals[i], hb, mb, lb);
        size_t base = ((size_t)(k>>4)*32 + (c>>5))*512 + (((k>>3)&1)*32 + (c&31))*8 + (k&7);
        cbp[base] = hb;
        cbp[base + (size_t)16*32*512] = mb;
        cbp[base + (size_t)2*16*32*512] = lb;
    }
}

// ---------- k_prep: [M|G] = convw^T @ [proj | convw] -> 3 bf16 planes; wsum; p1 ----------
// w2p[p][kc 16][nt 16][lane 64][8]: element (col, k): nt=col>>5, lane=((k>>3)&1)*32+(col&31), j=k&7
__global__ __launch_bounds__(256) void k_prep(const float* __restrict__ convw,
                                              const float* __restrict__ proj,
                                              ushort_t* __restrict__ w2p,
                                              float* __restrict__ wsum,
                                              float* __restrict__ p1) {
    int col = blockIdx.x, t = threadIdx.x;
    if (col < 512) {
        __shared__ float colv[512];
        const float* src = (col < 256) ? (proj + col) : (convw + (col - 256));
        colv[t]       = src[(size_t)t * 256];
        colv[t + 256] = src[(size_t)(t + 256) * 256];
        __syncthreads();
        float acc = 0.f;
        for (int d = 0; d < 512; ++d) acc += convw[d * 256 + t] * colv[d];
        int k = t;
        ushort_t hb, mb, lb; split3(acc, hb, mb, lb);
        size_t base = ((size_t)(k>>4)*16 + (col>>5))*512 + (((k>>3)&1)*32 + (col&31))*8 + (k&7);
        w2p[base] = hb;
        w2p[base + (size_t)16*16*512] = mb;
        w2p[base + (size_t)2*16*16*512] = lb;
    } else if (col == 512) {
        float s = 0.f;
        for (int d = 0; d < 512; ++d) s += convw[d*256 + t];
        wsum[t] = s;
    } else {
        float s = 0.f;
        for (int d = 0; d < 512; ++d) s += proj[d*256 + t];
        p1[t] = s;
    }
}

// ---------- k_mega: patches -> split -> GEMM1(MFMA) -> LN -> GEMM2(MFMA) -> argmax ----------
// 1024 blocks x 512 threads, 64 tokens/block. 32x32x16 bf16 MFMA, split-3 x 6 passes.
// A-frag: A[m=lane&31][k=8*(lane>>5)+j]; B-frag: B[n=lane&31][k=8*(lane>>5)+j];
// D: [row=(reg&3)+8*(reg>>2)+4*(lane>>5)][col=lane&31]  (m74/m101-verified layouts)
__global__ __launch_bounds__(512, 2) void k_mega(const float* __restrict__ fbank,
                                                 const ushort_t* __restrict__ w2p,
                                                 const ushort_t* __restrict__ cbp,
                                                 const float* __restrict__ wsum,
                                                 const float* __restrict__ p1,
                                                 int* __restrict__ out) {
    extern __shared__ char smem[];
    float* wsS  = (float*)(smem + WS);
    float* p1S  = (float*)(smem + P1O);
    float* muP  = (float*)(smem + MP);
    float* sqP  = (float*)(smem + SP);
    float* lnMu = (float*)(smem + LM);
    float* lnRs = (float*)(smem + LR);
    float* P32  = (float*)(smem + DB);     // [32][257] f32, stride 257 (bank-spread)

    int tid = threadIdx.x;
    int n0 = blockIdx.x * 64;
    int w = tid >> 6, lane = tid & 63;
    int n31 = lane & 31, h = lane >> 5;

    // prefetch first GEMM1 B-slice (seg0, kc0, plane 0)
    float4 g0, g1;
    {
        const char* gp = (const char*)w2p;
        g0 = *(const float4*)(gp + tid*16);
        g1 = *(const float4*)(gp + 8192 + tid*16);
    }
    if (tid < 256) wsS[tid] = wsum[tid];
    else           p1S[tid - 256] = p1[tid - 256];

    // ---- stage patches -> 3 bf16 planes; cell (mt,kc,cl): token=cl&31, k=16kc+8*(cl>>5)+j ----
    #pragma unroll
    for (int i = 0; i < 4; ++i) {
        int id = tid + 512*i;
        int mt = id >> 10, kc = (id >> 6) & 15, cl = id & 63;
        int tloc = cl & 31, hh2 = cl >> 5;
        int n = n0 + 32*mt + tloc;
        int b = n >> 12, r = n & 4095, th = r >> 3, wm = r & 7;
        const float* src = fbank + ((size_t)(b*TT + th*16 + kc))*128 + wm*16 + hh2*8;
        float4 va = *(const float4*)src;
        float4 vb = *(const float4*)(src + 4);
        float vals[8] = {va.x, va.y, va.z, va.w, vb.x, vb.y, vb.z, vb.w};
        us8 hv, mv, lv;
        #pragma unroll
        for (int j = 0; j < 8; ++j) {
            ushort_t a_, b_, c_; split3(vals[j], a_, b_, c_);
            hv[j] = a_; mv[j] = b_; lv[j] = c_;
        }
        char* cp = smem + PL + mt*16384 + kc*1024 + cl*16;
        *(us8*)cp = hv;
        *(us8*)(cp + 32768) = mv;
        *(us8*)(cp + 65536) = lv;
    }

    f32x16 acc[2][2];
    #pragma unroll
    for (int a = 0; a < 2; ++a)
        #pragma unroll
        for (int b2 = 0; b2 < 2; ++b2)
            #pragma unroll
            for (int r2 = 0; r2 < 16; ++r2) acc[a][b2][r2] = 0.f;

    int buf = 0;

    // ================= GEMM1: V[64][512] = patch @ [M|G], 6 passes x 16 kc =================
    for (int it = 0; it < 96; ++it) {
        // publish staged slice (regs -> dbuf[buf]); canonical tid*16
        *(float4*)(smem + DB + buf*16384 + tid*16)        = g0;
        *(float4*)(smem + DB + buf*16384 + 8192 + tid*16) = g1;
        // prefetch next slice
        {
            int nit = it + 1;
            const char* gp;
            if (nit < 96) {
                int s2 = nit >> 4, k2 = nit & 15;
                gp = (const char*)w2p + ((size_t)(pbOf(s2)*16 + k2) * 16384);
            } else {
                gp = (const char*)cbp;   // GEMM2 sweep0 seg0 kc0
            }
            g0 = *(const float4*)(gp + tid*16);
            g1 = *(const float4*)(gp + 8192 + tid*16);
        }
        __syncthreads();
        int seg = it >> 4, kc = it & 15;
        const char* aB = smem + PL + paOf(seg)*32768 + kc*1024 + lane*16;
        bf16x8 a0 = *(const bf16x8*)(aB);
        bf16x8 a1 = *(const bf16x8*)(aB + 16384);
        const char* bB = smem + DB + buf*16384 + (2*w)*1024 + lane*16;
        bf16x8 b0 = *(const bf16x8*)(bB);
        bf16x8 b1 = *(const bf16x8*)(bB + 1024);
        acc[0][0] = MF(a0, b0, acc[0][0]);
        acc[0][1] = MF(a0, b1, acc[0][1]);
        acc[1][0] = MF(a1, b0, acc[1][0]);
        acc[1][1] = MF(a1, b1, acc[1][1]);
        buf ^= 1;
    }

    // ================= LN epilogue =================
    #pragma unroll
    for (int mh = 0; mh < 2; ++mh) {
        __syncthreads();   // dbuf free / prior P32 readers done
        // rebuild fp32 patches of half mh into P32 (exact h+m+l)
        #pragma unroll
        for (int i = 0; i < 2; ++i) {
            int id = tid + 512*i;          // 1024 cells
            int kc = id >> 6, cl = id & 63;
            int tloc = cl & 31, hh2 = cl >> 5;
            const char* cp = smem + PL + mh*16384 + kc*1024 + cl*16;
            us8 hv = *(const us8*)(cp);
            us8 mv = *(const us8*)(cp + 32768);
            us8 lv = *(const us8*)(cp + 65536);
            float* dst = P32 + tloc*257 + kc*16 + hh2*8;
            #pragma unroll
            for (int j = 0; j < 8; ++j) dst[j] = rejoin(hv[j], mv[j], lv[j]);
        }
        __syncthreads();
        if (tid < 256) {               // mu partials: 8 threads per token
            int tk = tid >> 3, part = tid & 7;
            const float* pr = P32 + tk*257 + part*32;
            const float* wr = wsS + part*32;
            float s = 0.f;
            #pragma unroll
            for (int k = 0; k < 32; ++k) s += pr[k] * wr[k];
            muP[tk*8 + part] = s;
        }
        if (w >= 4) {                  // sumsq = V_G . patch (waves 4..7 hold G cols)
            int wv = w - 4;
            #pragma unroll
            for (int reg = 0; reg < 16; ++reg) {
                int row = (reg&3) + 8*(reg>>2) + 4*h;
                float sv = acc[mh][0][reg] * P32[row*257 + 64*wv + n31]
                         + acc[mh][1][reg] * P32[row*257 + 64*wv + 32 + n31];
                #pragma unroll
                for (int msk = 1; msk < 32; msk <<= 1) sv += __shfl_xor(sv, msk);
                if (n31 == 0) sqP[row*4 + wv] = sv;
            }
        }
        __syncthreads();
        if (tid < 32) {
            float pm = 0.f, sq = 0.f;
            #pragma unroll
            for (int p = 0; p < 8; ++p) pm += muP[tid*8 + p];
            #pragma unroll
            for (int v2 = 0; v2 < 4; ++v2) sq += sqP[tid*4 + v2];
            float m_ = pm * (1.f/512.f);
            float var = sq * (1.f/512.f) - m_*m_;
            lnMu[mh*32 + tid] = m_;
            lnRs[mh*32 + tid] = rsqrtf(var + 1e-5f);   // positive scale: argmax-neutral
        }
    }
    __syncthreads();
    // t = rs*(V - mu*p1), re-split into planes (waves 0..3 hold cols 0..255)
    if (w < 4) {
        #pragma unroll
        for (int mt = 0; mt < 2; ++mt)
            #pragma unroll
            for (int ntl = 0; ntl < 2; ++ntl) {
                int q = 32*(2*w + ntl) + n31;
                float p1v = p1S[q];
                #pragma unroll
                for (int reg = 0; reg < 16; ++reg) {
                    int row = (reg&3) + 8*(reg>>2) + 4*h;
                    int tk = 32*mt + row;
                    float tv = lnRs[tk] * (acc[mt][ntl][reg] - lnMu[tk]*p1v);
                    ushort_t hb, mb, lb; split3(tv, hb, mb, lb);
                    char* cp = smem + PL + mt*16384 + (q>>4)*1024
                             + (((q>>3)&1)*32 + row)*16 + (q&7)*2;
                    *(ushort_t*)cp = hb;
                    *(ushort_t*)(cp + 32768) = mb;
                    *(ushort_t*)(cp + 65536) = lb;
                }
            }
    }

    // ================= GEMM2 + argmax: sim = t @ cbn^T =================
    float bestV[2][16]; int bestIx[2][16];
    #pragma unroll
    for (int mt = 0; mt < 2; ++mt)
        #pragma unroll
        for (int reg = 0; reg < 16; ++reg) { bestV[mt][reg] = -3.4e38f; bestIx[mt][reg] = 0; }

    for (int sweep = 0; sweep < 2; ++sweep) {
        #pragma unroll
        for (int a = 0; a < 2; ++a)
            #pragma unroll
            for (int b2 = 0; b2 < 2; ++b2)
                #pragma unroll
                for (int r2 = 0; r2 < 16; ++r2) acc[a][b2][r2] = 0.f;

        for (int it2 = 0; it2 < 96; ++it2) {
            *(float4*)(smem + DB + buf*16384 + tid*16)        = g0;
            *(float4*)(smem + DB + buf*16384 + 8192 + tid*16) = g1;
            {
                bool last = (sweep == 1) && (it2 == 95);
                int nit = it2 + 1, ns = sweep;
                if (nit == 96) { nit = 0; ns = 1; }
                int s2 = nit >> 4, k2 = nit & 15;
                const char* gp = (const char*)cbp
                    + ((size_t)((pbOf(s2)*16 + k2)*32 + 16*ns) * 1024);
                if (!last) {
                    g0 = *(const float4*)(gp + tid*16);
                    g1 = *(const float4*)(gp + 8192 + tid*16);
                }
            }
            __syncthreads();
            int seg = it2 >> 4, kc = it2 & 15;
            const char* aB = smem + PL + paOf(seg)*32768 + kc*1024 + lane*16;
            bf16x8 a0 = *(const bf16x8*)(aB);
            bf16x8 a1 = *(const bf16x8*)(aB + 16384);
            const char* bB = smem + DB + buf*16384 + (2*w)*1024 + lane*16;
            bf16x8 b0 = *(const bf16x8*)(bB);
            bf16x8 b1 = *(const bf16x8*)(bB + 1024);
            acc[0][0] = MF(a0, b0, acc[0][0]);
            acc[0][1] = MF(a0, b1, acc[0][1]);
            acc[1][0] = MF(a1, b0, acc[1][0]);
            acc[1][1] = MF(a1, b1, acc[1][1]);
            buf ^= 1;
        }
        // fold sweep (ascending code, strict > : first-max tie-break)
        #pragma unroll
        for (int mt = 0; mt < 2; ++mt)
            #pragma unroll
            for (int ntl = 0; ntl < 2; ++ntl) {
                int codeBase = 512*sweep + 32*(2*w + ntl) + n31;
                #pragma unroll
                for (int reg = 0; reg < 16; ++reg) {
                    float v = acc[mt][ntl][reg];
                    if (v > bestV[mt][reg]) { bestV[mt][reg] = v; bestIx[mt][reg] = codeBase; }
                }
            }
    }

    // cross-lane (32 code-lanes) then cross-wave reduction, lowest-index-on-tie
    float* redV = (float*)(smem + RV);
    int*   redI = (int*)(smem + RI);
    #pragma unroll
    for (int mt = 0; mt < 2; ++mt)
        #pragma unroll
        for (int reg = 0; reg < 16; ++reg) {
            float bv = bestV[mt][reg]; int bi = bestIx[mt][reg];
            #pragma unroll
            for (int msk = 1; msk < 32; msk <<= 1) {
                float ov = __shfl_xor(bv, msk);
                int   oi = __shfl_xor(bi, msk);
                if (ov > bv || (ov == bv && oi < bi)) { bv = ov; bi = oi; }
            }
            if (n31 == 0) {
                int row = (reg&3) + 8*(reg>>2) + 4*h;
                int tk = 32*mt + row;
                redV[tk*8 + w] = bv;
                redI[tk*8 + w] = bi;
            }
        }
    __syncthreads();
    if (tid < 64) {
        float bv = redV[tid*8]; int bi = redI[tid*8];
        #pragma unroll
        for (int p = 1; p < 8; ++p) {
            float ov = redV[tid*8 + p]; int oi = redI[tid*8 + p];
            if (ov > bv || (ov == bv && oi < bi)) { bv = ov; bi = oi; }
        }
        out[n0 + tid] = bi;
    }
}

extern "C" void kernel_launch(void* const* d_in, const int* in_sizes, int n_in,
                              void* d_out, int out_size, void* d_ws, size_t ws_size,
                              hipStream_t stream) {
    const float* fbank = (const float*)d_in[0];   // 16 x 8192 x 128
    const float* convw = (const float*)d_in[1];   // [512][256]
    const float* proj  = (const float*)d_in[2];   // [512][256]
    const float* cbook = (const float*)d_in[3];   // [1024][256]
    int* out = (int*)d_out;                       // 65536 int32

    char* ws = (char*)d_ws;
    ushort_t* cbp = (ushort_t*)ws;                   // 1.5 MB code planes
    ushort_t* w2p = (ushort_t*)(ws + 0x180000);      // 768 KB weight planes
    float* wsum   = (float*)(ws + 0x240000);         // 1 KB
    float* p1     = (float*)(ws + 0x241000);         // 1 KB

    (void)hipFuncSetAttribute((const void*)k_mega,
                              hipFuncAttributeMaxDynamicSharedMemorySize, SMEM_TOTAL);

    hipLaunchKernelGGL(k_cbnorm, dim3(QN),  dim3(64),  0, stream, cbook, cbp);
    hipLaunchKernelGGL(k_prep,   dim3(514), dim3(256), 0, stream, convw, proj, w2p, wsum, p1);
    hipLaunchKernelGGL(k_mega,   dim3(NTOK/64), dim3(512), SMEM_TOTAL, stream,
                       fbank, w2p, cbp, wsum, p1, out);
}

// Round 9
// 501.016 us; speedup vs baseline: 10.5583x; 1.3157x over previous
//
#include <hip/hip_runtime.h>
#include <math.h>

#define QD 256
#define QN 1024
#define NTOK 65536
#define TT 8192

typedef __bf16 bf16x8 __attribute__((ext_vector_type(8)));
typedef float  f32x16 __attribute__((ext_vector_type(16)));
typedef unsigned short ushort_t;
typedef unsigned short us8 __attribute__((ext_vector_type(8)));

// LDS byte offsets (k_mega), total 139264
#define PL 0          // bf16 planes [3][2 mt][16 kc][64 cl][16B] = 98304 (plane stride 32768)
#define DB 98304      // B dbuf [2][16KB] = 32768 ; reused as P32[32][257] f32 in LN
#define RV 131072     // redV [64][8] f32
#define RI 133120     // redI [64][8] i32
#define WS 135168     // wsS [256] f32
#define P1O 136192    // p1S [256] f32
#define MP 137216     // muP [32][8] f32
#define SP 138240     // sqP [32][4] f32
#define LM 138752     // lnMu [64]
#define LR 139008     // lnRs [64]
#define SMEM_TOTAL 139264

// exact 3-way bf16 split (truncation; x = h+m+l up to ~2^-25|x|)
__device__ __forceinline__ void split3(float x, ushort_t& h, ushort_t& m, ushort_t& l) {
    unsigned int xu = __float_as_uint(x);
    h = (ushort_t)(xu >> 16);
    float hf = __uint_as_float(xu & 0xFFFF0000u);
    float r1 = x - hf;                       // exact
    unsigned int r1u = __float_as_uint(r1);
    m = (ushort_t)(r1u >> 16);
    float mf = __uint_as_float(r1u & 0xFFFF0000u);
    float r2 = r1 - mf;                      // exact
    l = (ushort_t)(__float_as_uint(r2) >> 16);
}
__device__ __forceinline__ float rejoin(ushort_t h, ushort_t m, ushort_t l) {
    return __uint_as_float((unsigned)h << 16) + __uint_as_float((unsigned)m << 16)
         + __uint_as_float((unsigned)l << 16);
}
__device__ __forceinline__ f32x16 MF(bf16x8 a, bf16x8 b, f32x16 c) {
    return __builtin_amdgcn_mfma_f32_32x32x16_bf16(a, b, c, 0, 0, 0);
}
// async global->LDS DMA, 16B per lane, dest = wave-uniform base + lane*16
__device__ __forceinline__ void dma16(const void* g, void* l) {
    __builtin_amdgcn_global_load_lds(
        (const __attribute__((address_space(1))) unsigned int*)g,
        (__attribute__((address_space(3))) unsigned int*)l, 16, 0, 0);
}

// ---------- k_cbnorm: l2-normalize codebook -> 3 bf16 planes in frag layout ----------
// cbp[p][kc 16][nt 32][lane 64][8]: element (code c, k): nt=c>>5, lane=((k>>3)&1)*32+(c&31), j=k&7
__global__ __launch_bounds__(64) void k_cbnorm(const float* __restrict__ cb,
                                               ushort_t* __restrict__ cbp) {
    int c = blockIdx.x, lane = threadIdx.x;
    float4 v = ((const float4*)(cb + (size_t)c * QD))[lane];
    float ss = v.x*v.x + v.y*v.y + v.z*v.z + v.w*v.w;
    #pragma unroll
    for (int off = 32; off > 0; off >>= 1) ss += __shfl_down(ss, off);
    ss = __shfl(ss, 0);
    float inv = 1.0f / fmaxf(sqrtf(ss), 1e-12f);
    float vals[4] = {v.x*inv, v.y*inv, v.z*inv, v.w*inv};
    #pragma unroll
    for (int i = 0; i < 4; ++i) {
        int k = 4*lane + i;
        ushort_t hb, mb, lb; split3(vals[i], hb, mb, lb);
        size_t base = ((size_t)(k>>4)*32 + (c>>5))*512 + (((k>>3)&1)*32 + (c&31))*8 + (k&7);
        cbp[base] = hb;
        cbp[base + (size_t)16*32*512] = mb;
        cbp[base + (size_t)2*16*32*512] = lb;
    }
}

// ---------- k_prep: [M|G] = convw^T @ [proj | convw] -> 3 bf16 planes; wsum; p1 ----------
// w2p[p][kc 16][nt 16][lane 64][8]: element (col, k): nt=col>>5, lane=((k>>3)&1)*32+(col&31), j=k&7
__global__ __launch_bounds__(256) void k_prep(const float* __restrict__ convw,
                                              const float* __restrict__ proj,
                                              ushort_t* __restrict__ w2p,
                                              float* __restrict__ wsum,
                                              float* __restrict__ p1) {
    int col = blockIdx.x, t = threadIdx.x;
    if (col < 512) {
        __shared__ float colv[512];
        const float* src = (col < 256) ? (proj + col) : (convw + (col - 256));
        colv[t]       = src[(size_t)t * 256];
        colv[t + 256] = src[(size_t)(t + 256) * 256];
        __syncthreads();
        float acc = 0.f;
        for (int d = 0; d < 512; ++d) acc += convw[d * 256 + t] * colv[d];
        int k = t;
        ushort_t hb, mb, lb; split3(acc, hb, mb, lb);
        size_t base = ((size_t)(k>>4)*16 + (col>>5))*512 + (((k>>3)&1)*32 + (col&31))*8 + (k&7);
        w2p[base] = hb;
        w2p[base + (size_t)16*16*512] = mb;
        w2p[base + (size_t)2*16*16*512] = lb;
    } else if (col == 512) {
        float s = 0.f;
        for (int d = 0; d < 512; ++d) s += convw[d*256 + t];
        wsum[t] = s;
    } else {
        float s = 0.f;
        for (int d = 0; d < 512; ++d) s += proj[d*256 + t];
        p1[t] = s;
    }
}

// ---------- k_mega: patches -> split -> GEMM1(MFMA) -> LN -> GEMM2(MFMA) -> argmax ----------
// 1024 blocks x 512 threads, 64 tokens/block. Split-3 products = pairs (pA,qB) with pA+qB<=2.
// B-plane-major K-loop: stage (q,kc) B-slice via global_load_lds dbuf, multiply by A-planes
// 0..2-q (A-frags register-resident across the 3 q-stages of a kc). 144 barrier stages total.
__global__ __launch_bounds__(512, 2) void k_mega(const float* __restrict__ fbank,
                                                 const ushort_t* __restrict__ w2p,
                                                 const ushort_t* __restrict__ cbp,
                                                 const float* __restrict__ wsum,
                                                 const float* __restrict__ p1,
                                                 int* __restrict__ out) {
    extern __shared__ char smem[];
    float* wsS  = (float*)(smem + WS);
    float* p1S  = (float*)(smem + P1O);
    float* muP  = (float*)(smem + MP);
    float* sqP  = (float*)(smem + SP);
    float* lnMu = (float*)(smem + LM);
    float* lnRs = (float*)(smem + LR);
    float* P32  = (float*)(smem + DB);     // [32][257] f32 (spills 128B into RV region; RV used later)

    int tid = threadIdx.x;
    int n0 = blockIdx.x * 64;
    int w = tid >> 6, lane = tid & 63;
    int n31 = lane & 31, h = lane >> 5;
    const char* w2pc = (const char*)w2p;
    const char* cbpc = (const char*)cbp;
    size_t toff = (size_t)tid * 16;

    // issue DMA for GEMM1 stage 0 (q=0,kc=0) into buf0 immediately
    dma16(w2pc + toff,        smem + DB + toff);
    dma16(w2pc + 8192 + toff, smem + DB + 8192 + toff);

    if (tid < 256) wsS[tid] = wsum[tid];
    else           p1S[tid - 256] = p1[tid - 256];

    // ---- stage patches -> 3 bf16 planes; cell (mt,kc,cl): token=cl&31, k=16kc+8*(cl>>5)+j ----
    #pragma unroll
    for (int i = 0; i < 4; ++i) {
        int id = tid + 512*i;
        int mt = id >> 10, kc = (id >> 6) & 15, cl = id & 63;
        int tloc = cl & 31, hh2 = cl >> 5;
        int n = n0 + 32*mt + tloc;
        int b = n >> 12, r = n & 4095, th = r >> 3, wm = r & 7;
        const float* src = fbank + ((size_t)(b*TT + th*16 + kc))*128 + wm*16 + hh2*8;
        float4 va = *(const float4*)src;
        float4 vb = *(const float4*)(src + 4);
        float vals[8] = {va.x, va.y, va.z, va.w, vb.x, vb.y, vb.z, vb.w};
        us8 hv, mv, lv;
        #pragma unroll
        for (int j = 0; j < 8; ++j) {
            ushort_t a_, b_, c_; split3(vals[j], a_, b_, c_);
            hv[j] = a_; mv[j] = b_; lv[j] = c_;
        }
        char* cp = smem + PL + mt*16384 + kc*1024 + cl*16;
        *(us8*)cp = hv;
        *(us8*)(cp + 32768) = mv;
        *(us8*)(cp + 65536) = lv;
    }

    f32x16 acc[2][2];
    #pragma unroll
    for (int a = 0; a < 2; ++a)
        #pragma unroll
        for (int b2 = 0; b2 < 2; ++b2)
            #pragma unroll
            for (int r2 = 0; r2 < 16; ++r2) acc[a][b2][r2] = 0.f;

    // ================= GEMM1: V[64][512] = patch @ [M|G] =================
    for (int kc = 0; kc < 16; ++kc) {
        bf16x8 a[3][2];
        #pragma unroll
        for (int q = 0; q < 3; ++q) {
            __syncthreads();   // drains DMA for this stage (and publishes planes at stage 0)
            // prefetch next stage AFTER barrier (full compute phase to complete)
            if (q < 2 || kc < 15) {
                int q2  = (q == 2) ? 0 : q + 1;
                int kc2 = (q == 2) ? kc + 1 : kc;
                const char* gp = w2pc + (size_t)(q2*16 + kc2) * 16384;
                char* lp = smem + DB + (((kc*3 + q + 1) & 1) ? 16384 : 0);
                dma16(gp + toff,        lp + toff);
                dma16(gp + 8192 + toff, lp + 8192 + toff);
            }
            if (q == 0) {
                #pragma unroll
                for (int p = 0; p < 3; ++p)
                    #pragma unroll
                    for (int mt = 0; mt < 2; ++mt)
                        a[p][mt] = *(const bf16x8*)(smem + PL + p*32768 + mt*16384
                                                    + kc*1024 + lane*16);
            }
            const char* bB = smem + DB + (((kc*3 + q) & 1) ? 16384 : 0) + (2*w)*1024 + lane*16;
            bf16x8 b0 = *(const bf16x8*)bB;
            bf16x8 b1 = *(const bf16x8*)(bB + 1024);
            #pragma unroll
            for (int p = 0; p < 3; ++p) {
                if (p <= 2 - q) {
                    acc[0][0] = MF(a[p][0], b0, acc[0][0]);
                    acc[0][1] = MF(a[p][0], b1, acc[0][1]);
                    acc[1][0] = MF(a[p][1], b0, acc[1][0]);
                    acc[1][1] = MF(a[p][1], b1, acc[1][1]);
                }
            }
        }
    }

    // ================= LN epilogue =================
    #pragma unroll
    for (int mh = 0; mh < 2; ++mh) {
        __syncthreads();   // dbuf reads done / prior P32 readers done
        // rebuild fp32 patches of half mh into P32 (exact h+m+l)
        #pragma unroll
        for (int i = 0; i < 2; ++i) {
            int id = tid + 512*i;          // 1024 cells
            int kc = id >> 6, cl = id & 63;
            int tloc = cl & 31, hh2 = cl >> 5;
            const char* cp = smem + PL + mh*16384 + kc*1024 + cl*16;
            us8 hv = *(const us8*)(cp);
            us8 mv = *(const us8*)(cp + 32768);
            us8 lv = *(const us8*)(cp + 65536);
            float* dst = P32 + tloc*257 + kc*16 + hh2*8;
            #pragma unroll
            for (int j = 0; j < 8; ++j) dst[j] = rejoin(hv[j], mv[j], lv[j]);
        }
        __syncthreads();
        if (tid < 256) {               // mu partials: 8 threads per token
            int tk = tid >> 3, part = tid & 7;
            const float* pr = P32 + tk*257 + part*32;
            const float* wr = wsS + part*32;
            float s = 0.f;
            #pragma unroll
            for (int k = 0; k < 32; ++k) s += pr[k] * wr[k];
            muP[tk*8 + part] = s;
        }
        if (w >= 4) {                  // sumsq = V_G . patch (waves 4..7 hold G cols)
            int wv = w - 4;
            #pragma unroll
            for (int reg = 0; reg < 16; ++reg) {
                int row = (reg&3) + 8*(reg>>2) + 4*h;
                float sv = acc[mh][0][reg] * P32[row*257 + 64*wv + n31]
                         + acc[mh][1][reg] * P32[row*257 + 64*wv + 32 + n31];
                #pragma unroll
                for (int msk = 1; msk < 32; msk <<= 1) sv += __shfl_xor(sv, msk);
                if (n31 == 0) sqP[row*4 + wv] = sv;
            }
        }
        __syncthreads();
        if (tid < 32) {
            float pm = 0.f, sq = 0.f;
            #pragma unroll
            for (int p = 0; p < 8; ++p) pm += muP[tid*8 + p];
            #pragma unroll
            for (int v2 = 0; v2 < 4; ++v2) sq += sqP[tid*4 + v2];
            float m_ = pm * (1.f/512.f);
            float var = sq * (1.f/512.f) - m_*m_;
            lnMu[mh*32 + tid] = m_;
            lnRs[mh*32 + tid] = rsqrtf(var + 1e-5f);   // positive scale: argmax-neutral
        }
    }
    __syncthreads();   // publishes lnMu/lnRs; P32 (=DB) now dead
    // issue DMA for GEMM2 stage 0 (sweep0,kc0,q0) into buf0
    dma16(cbpc + toff,        smem + DB + toff);
    dma16(cbpc + 8192 + toff, smem + DB + 8192 + toff);

    // t = rs*(V - mu*p1), re-split into planes (waves 0..3 hold cols 0..255)
    if (w < 4) {
        #pragma unroll
        for (int mt = 0; mt < 2; ++mt)
            #pragma unroll
            for (int ntl = 0; ntl < 2; ++ntl) {
                int q = 32*(2*w + ntl) + n31;
                float p1v = p1S[q];
                #pragma unroll
                for (int reg = 0; reg < 16; ++reg) {
                    int row = (reg&3) + 8*(reg>>2) + 4*h;
                    int tk = 32*mt + row;
                    float tv = lnRs[tk] * (acc[mt][ntl][reg] - lnMu[tk]*p1v);
                    ushort_t hb, mb, lb; split3(tv, hb, mb, lb);
                    char* cp = smem + PL + mt*16384 + (q>>4)*1024
                             + (((q>>3)&1)*32 + row)*16 + (q&7)*2;
                    *(ushort_t*)cp = hb;
                    *(ushort_t*)(cp + 32768) = mb;
                    *(ushort_t*)(cp + 65536) = lb;
                }
            }
    }

    // ================= GEMM2 + argmax: sim = t @ cbn^T =================
    float bestV[2][16]; int bestIx[2][16];
    #pragma unroll
    for (int mt = 0; mt < 2; ++mt)
        #pragma unroll
        for (int reg = 0; reg < 16; ++reg) { bestV[mt][reg] = -3.4e38f; bestIx[mt][reg] = 0; }

    for (int sweep = 0; sweep < 2; ++sweep) {
        #pragma unroll
        for (int a = 0; a < 2; ++a)
            #pragma unroll
            for (int b2 = 0; b2 < 2; ++b2)
                #pragma unroll
                for (int r2 = 0; r2 < 16; ++r2) acc[a][b2][r2] = 0.f;

        for (int kc = 0; kc < 16; ++kc) {
            bf16x8 a[3][2];
            #pragma unroll
            for (int q = 0; q < 3; ++q) {
                __syncthreads();   // drains DMA for this stage (sweep0/kc0/q0: publishes t-planes)
                if (!(sweep == 1 && kc == 15 && q == 2)) {
                    int q2  = (q == 2) ? 0 : q + 1;
                    int kc2 = (q == 2) ? ((kc == 15) ? 0 : kc + 1) : kc;
                    int sw2 = (q == 2 && kc == 15) ? sweep + 1 : sweep;
                    const char* gp = cbpc + (size_t)(q2*16 + kc2)*32768 + (size_t)sw2*16384;
                    char* lp = smem + DB + (((kc*3 + q + 1) & 1) ? 16384 : 0);
                    dma16(gp + toff,        lp + toff);
                    dma16(gp + 8192 + toff, lp + 8192 + toff);
                }
                if (q == 0) {
                    #pragma unroll
                    for (int p = 0; p < 3; ++p)
                        #pragma unroll
                        for (int mt = 0; mt < 2; ++mt)
                            a[p][mt] = *(const bf16x8*)(smem + PL + p*32768 + mt*16384
                                                        + kc*1024 + lane*16);
                }
                const char* bB = smem + DB + (((kc*3 + q) & 1) ? 16384 : 0) + (2*w)*1024 + lane*16;
                bf16x8 b0 = *(const bf16x8*)bB;
                bf16x8 b1 = *(const bf16x8*)(bB + 1024);
                #pragma unroll
                for (int p = 0; p < 3; ++p) {
                    if (p <= 2 - q) {
                        acc[0][0] = MF(a[p][0], b0, acc[0][0]);
                        acc[0][1] = MF(a[p][0], b1, acc[0][1]);
                        acc[1][0] = MF(a[p][1], b0, acc[1][0]);
                        acc[1][1] = MF(a[p][1], b1, acc[1][1]);
                    }
                }
            }
        }
        // fold sweep (ascending code, strict > : first-max tie-break)
        #pragma unroll
        for (int mt = 0; mt < 2; ++mt)
            #pragma unroll
            for (int ntl = 0; ntl < 2; ++ntl) {
                int codeBase = 512*sweep + 32*(2*w + ntl) + n31;
                #pragma unroll
                for (int reg = 0; reg < 16; ++reg) {
                    float v = acc[mt][ntl][reg];
                    if (v > bestV[mt][reg]) { bestV[mt][reg] = v; bestIx[mt][reg] = codeBase; }
                }
            }
    }

    // cross-lane (32 code-lanes) then cross-wave reduction, lowest-index-on-tie
    float* redV = (float*)(smem + RV);
    int*   redI = (int*)(smem + RI);
    #pragma unroll
    for (int mt = 0; mt < 2; ++mt)
        #pragma unroll
        for (int reg = 0; reg < 16; ++reg) {
            float bv = bestV[mt][reg]; int bi = bestIx[mt][reg];
            #pragma unroll
            for (int msk = 1; msk < 32; msk <<= 1) {
                float ov = __shfl_xor(bv, msk);
                int   oi = __shfl_xor(bi, msk);
                if (ov > bv || (ov == bv && oi < bi)) { bv = ov; bi = oi; }
            }
            if (n31 == 0) {
                int row = (reg&3) + 8*(reg>>2) + 4*h;
                int tk = 32*mt + row;
                redV[tk*8 + w] = bv;
                redI[tk*8 + w] = bi;
            }
        }
    __syncthreads();
    if (tid < 64) {
        float bv = redV[tid*8]; int bi = redI[tid*8];
        #pragma unroll
        for (int p = 1; p < 8; ++p) {
            float ov = redV[tid*8 + p]; int oi = redI[tid*8 + p];
            if (ov > bv || (ov == bv && oi < bi)) { bv = ov; bi = oi; }
        }
        out[n0 + tid] = bi;
    }
}

extern "C" void kernel_launch(void* const* d_in, const int* in_sizes, int n_in,
                              void* d_out, int out_size, void* d_ws, size_t ws_size,
                              hipStream_t stream) {
    const float* fbank = (const float*)d_in[0];   // 16 x 8192 x 128
    const float* convw = (const float*)d_in[1];   // [512][256]
    const float* proj  = (const float*)d_in[2];   // [512][256]
    const float* cbook = (const float*)d_in[3];   // [1024][256]
    int* out = (int*)d_out;                       // 65536 int32

    char* ws = (char*)d_ws;
    ushort_t* cbp = (ushort_t*)ws;                   // 1.5 MB code planes
    ushort_t* w2p = (ushort_t*)(ws + 0x180000);      // 768 KB weight planes
    float* wsum   = (float*)(ws + 0x240000);         // 1 KB
    float* p1     = (float*)(ws + 0x241000);         // 1 KB

    (void)hipFuncSetAttribute((const void*)k_mega,
                              hipFuncAttributeMaxDynamicSharedMemorySize, SMEM_TOTAL);

    hipLaunchKernelGGL(k_cbnorm, dim3(QN),  dim3(64),  0, stream, cbook, cbp);
    hipLaunchKernelGGL(k_prep,   dim3(514), dim3(256), 0, stream, convw, proj, w2p, wsum, p1);
    hipLaunchKernelGGL(k_mega,   dim3(NTOK/64), dim3(512), SMEM_TOTAL, stream,
                       fbank, w2p, cbp, wsum, p1, out);
}

// Round 10
// 461.900 us; speedup vs baseline: 11.4524x; 1.0847x over previous
//
#include <hip/hip_runtime.h>
#include <math.h>

#define QD 256
#define QN 1024
#define NTOK 65536
#define TT 8192

typedef __bf16 bf16x8 __attribute__((ext_vector_type(8)));
typedef float  f32x16 __attribute__((ext_vector_type(16)));
typedef unsigned short ushort_t;
typedef unsigned short us8 __attribute__((ext_vector_type(8)));

// LDS byte offsets (k_mega), total 139264
#define PL 0          // bf16 planes [3][2 mt][16 kc][64 cl][16B] = 98304 (plane stride 32768)
#define DB 98304      // P32[32][257] f32 in LN (B staging is now global->VGPR, no LDS dbuf)
#define RV 131072     // redV [64][8] f32
#define RI 133120     // redI [64][8] i32
#define WS 135168     // wsS [256] f32
#define P1O 136192    // p1S [256] f32
#define MP 137216     // muP [32][8] f32
#define SP 138240     // sqP [32][4] f32
#define LM 138752     // lnMu [64]
#define LR 139008     // lnRs [64]
#define SMEM_TOTAL 139264

// exact 3-way bf16 split (truncation; x = h+m+l up to ~2^-25|x|)
__device__ __forceinline__ void split3(float x, ushort_t& h, ushort_t& m, ushort_t& l) {
    unsigned int xu = __float_as_uint(x);
    h = (ushort_t)(xu >> 16);
    float hf = __uint_as_float(xu & 0xFFFF0000u);
    float r1 = x - hf;                       // exact
    unsigned int r1u = __float_as_uint(r1);
    m = (ushort_t)(r1u >> 16);
    float mf = __uint_as_float(r1u & 0xFFFF0000u);
    float r2 = r1 - mf;                      // exact
    l = (ushort_t)(__float_as_uint(r2) >> 16);
}
__device__ __forceinline__ float rejoin(ushort_t h, ushort_t m, ushort_t l) {
    return __uint_as_float((unsigned)h << 16) + __uint_as_float((unsigned)m << 16)
         + __uint_as_float((unsigned)l << 16);
}
__device__ __forceinline__ f32x16 MF(bf16x8 a, bf16x8 b, f32x16 c) {
    return __builtin_amdgcn_mfma_f32_32x32x16_bf16(a, b, c, 0, 0, 0);
}

// ---------- k_cbnorm: l2-normalize codebook -> 3 bf16 planes in frag layout ----------
// cbp[p][kc 16][nt 32][lane 64][8]: element (code c, k): nt=c>>5, lane=((k>>3)&1)*32+(c&31), j=k&7
__global__ __launch_bounds__(64) void k_cbnorm(const float* __restrict__ cb,
                                               ushort_t* __restrict__ cbp) {
    int c = blockIdx.x, lane = threadIdx.x;
    float4 v = ((const float4*)(cb + (size_t)c * QD))[lane];
    float ss = v.x*v.x + v.y*v.y + v.z*v.z + v.w*v.w;
    #pragma unroll
    for (int off = 32; off > 0; off >>= 1) ss += __shfl_down(ss, off);
    ss = __shfl(ss, 0);
    float inv = 1.0f / fmaxf(sqrtf(ss), 1e-12f);
    float vals[4] = {v.x*inv, v.y*inv, v.z*inv, v.w*inv};
    #pragma unroll
    for (int i = 0; i < 4; ++i) {
        int k = 4*lane + i;
        ushort_t hb, mb, lb; split3(vals[i], hb, mb, lb);
        size_t base = ((size_t)(k>>4)*32 + (c>>5))*512 + (((k>>3)&1)*32 + (c&31))*8 + (k&7);
        cbp[base] = hb;
        cbp[base + (size_t)16*32*512] = mb;
        cbp[base + (size_t)2*16*32*512] = lb;
    }
}

// ---------- k_prep: [M|G] = convw^T @ [proj | convw] -> 3 bf16 planes; wsum; p1 ----------
// w2p[p][kc 16][nt 16][lane 64][8]: element (col, k): nt=col>>5, lane=((k>>3)&1)*32+(col&31), j=k&7
__global__ __launch_bounds__(256) void k_prep(const float* __restrict__ convw,
                                              const float* __restrict__ proj,
                                              ushort_t* __restrict__ w2p,
                                              float* __restrict__ wsum,
                                              float* __restrict__ p1) {
    int col = blockIdx.x, t = threadIdx.x;
    if (col < 512) {
        __shared__ float colv[512];
        const float* src = (col < 256) ? (proj + col) : (convw + (col - 256));
        colv[t]       = src[(size_t)t * 256];
        colv[t + 256] = src[(size_t)(t + 256) * 256];
        __syncthreads();
        float acc = 0.f;
        for (int d = 0; d < 512; ++d) acc += convw[d * 256 + t] * colv[d];
        int k = t;
        ushort_t hb, mb, lb; split3(acc, hb, mb, lb);
        size_t base = ((size_t)(k>>4)*16 + (col>>5))*512 + (((k>>3)&1)*32 + (col&31))*8 + (k&7);
        w2p[base] = hb;
        w2p[base + (size_t)16*16*512] = mb;
        w2p[base + (size_t)2*16*16*512] = lb;
    } else if (col == 512) {
        float s = 0.f;
        for (int d = 0; d < 512; ++d) s += convw[d*256 + t];
        wsum[t] = s;
    } else {
        float s = 0.f;
        for (int d = 0; d < 512; ++d) s += proj[d*256 + t];
        p1[t] = s;
    }
}

// ---------- k_mega: patches -> split -> GEMM1(MFMA) -> LN -> GEMM2(MFMA) -> argmax ----------
// 1024 blocks x 512 threads, 64 tokens/block. Split-3 products = pairs (pA,qB), pA+qB<=2.
// BARRIER-FREE K-loops: A-planes LDS-resident (one barrier after staging); B-fragments
// loaded global->VGPR per wave (lane-contiguous dwordx4 from L2-resident planes) with a
// 2-stage ping-pong, so the compiler pipelines with fine-grained vmcnt (AITER pattern).
__global__ __launch_bounds__(512, 2) void k_mega(const float* __restrict__ fbank,
                                                 const ushort_t* __restrict__ w2p,
                                                 const ushort_t* __restrict__ cbp,
                                                 const float* __restrict__ wsum,
                                                 const float* __restrict__ p1,
                                                 int* __restrict__ out) {
    extern __shared__ char smem[];
    float* wsS  = (float*)(smem + WS);
    float* p1S  = (float*)(smem + P1O);
    float* muP  = (float*)(smem + MP);
    float* sqP  = (float*)(smem + SP);
    float* lnMu = (float*)(smem + LM);
    float* lnRs = (float*)(smem + LR);
    float* P32  = (float*)(smem + DB);     // [32][257] f32 (tail overlaps RV; RV used later)

    int tid = threadIdx.x;
    int n0 = blockIdx.x * 64;
    int w = tid >> 6, lane = tid & 63;
    int n31 = lane & 31, h = lane >> 5;
    const char* w2pc = (const char*)w2p;
    const char* cbpc = (const char*)cbp;
    size_t loff = (size_t)lane * 16;

    f32x16 acc[2][2];
    bf16x8 bA[3][2], bB[3][2];

    auto loadB1 = [&](int kcv, bf16x8 (&dst)[3][2]) {
        #pragma unroll
        for (int q = 0; q < 3; ++q)
            #pragma unroll
            for (int ntl = 0; ntl < 2; ++ntl)
                dst[q][ntl] = *(const bf16x8*)(w2pc
                    + (size_t)((q*16 + kcv)*16 + 2*w + ntl)*1024 + loff);
    };
    auto loadB2 = [&](int sw, int kcv, bf16x8 (&dst)[3][2]) {
        #pragma unroll
        for (int q = 0; q < 3; ++q)
            #pragma unroll
            for (int ntl = 0; ntl < 2; ++ntl)
                dst[q][ntl] = *(const bf16x8*)(cbpc
                    + (size_t)((q*16 + kcv)*32 + 16*sw + 2*w + ntl)*1024 + loff);
    };
    auto loadA = [&](int kcv, bf16x8 (&a)[3][2]) {
        #pragma unroll
        for (int p = 0; p < 3; ++p)
            #pragma unroll
            for (int mt = 0; mt < 2; ++mt)
                a[p][mt] = *(const bf16x8*)(smem + PL + p*32768 + mt*16384
                                            + kcv*1024 + loff);
    };
    auto compute = [&](bf16x8 (&a)[3][2], bf16x8 (&b)[3][2]) {
        #pragma unroll
        for (int q = 0; q < 3; ++q)
            #pragma unroll
            for (int p = 0; p < 3; ++p)
                if (p + q <= 2) {
                    acc[0][0] = MF(a[p][0], b[q][0], acc[0][0]);
                    acc[0][1] = MF(a[p][0], b[q][1], acc[0][1]);
                    acc[1][0] = MF(a[p][1], b[q][0], acc[1][0]);
                    acc[1][1] = MF(a[p][1], b[q][1], acc[1][1]);
                }
    };

    loadB1(0, bA);           // in flight under patch staging (drained once at the barrier)

    if (tid < 256) wsS[tid] = wsum[tid];
    else           p1S[tid - 256] = p1[tid - 256];

    // ---- stage patches -> 3 bf16 planes; cell (mt,kc,cl): token=cl&31, k=16kc+8*(cl>>5)+j ----
    #pragma unroll
    for (int i = 0; i < 4; ++i) {
        int id = tid + 512*i;
        int mt = id >> 10, kc = (id >> 6) & 15, cl = id & 63;
        int tloc = cl & 31, hh2 = cl >> 5;
        int n = n0 + 32*mt + tloc;
        int b = n >> 12, r = n & 4095, th = r >> 3, wm = r & 7;
        const float* src = fbank + ((size_t)(b*TT + th*16 + kc))*128 + wm*16 + hh2*8;
        float4 va = *(const float4*)src;
        float4 vb = *(const float4*)(src + 4);
        float vals[8] = {va.x, va.y, va.z, va.w, vb.x, vb.y, vb.z, vb.w};
        us8 hv, mv, lv;
        #pragma unroll
        for (int j = 0; j < 8; ++j) {
            ushort_t a_, b_, c_; split3(vals[j], a_, b_, c_);
            hv[j] = a_; mv[j] = b_; lv[j] = c_;
        }
        char* cp = smem + PL + mt*16384 + kc*1024 + cl*16;
        *(us8*)cp = hv;
        *(us8*)(cp + 32768) = mv;
        *(us8*)(cp + 65536) = lv;
    }

    #pragma unroll
    for (int a = 0; a < 2; ++a)
        #pragma unroll
        for (int b2 = 0; b2 < 2; ++b2)
            #pragma unroll
            for (int r2 = 0; r2 < 16; ++r2) acc[a][b2][r2] = 0.f;

    __syncthreads();         // publish A-planes (only barrier before GEMM1)

    // ================= GEMM1: V[64][512] = patch @ [M|G], barrier-free =================
    for (int kc = 0; kc < 16; kc += 2) {
        bf16x8 a[3][2];
        loadB1(kc + 1, bB);
        loadA(kc, a);
        compute(a, bA);
        if (kc + 2 < 16) loadB1(kc + 2, bA);
        loadA(kc + 1, a);
        compute(a, bB);
    }

    // ================= LN epilogue =================
    #pragma unroll
    for (int mh = 0; mh < 2; ++mh) {
        __syncthreads();   // all waves past GEMM1 / prior P32 readers done
        // rebuild fp32 patches of half mh into P32 (exact h+m+l)
        #pragma unroll
        for (int i = 0; i < 2; ++i) {
            int id = tid + 512*i;          // 1024 cells
            int kc = id >> 6, cl = id & 63;
            int tloc = cl & 31, hh2 = cl >> 5;
            const char* cp = smem + PL + mh*16384 + kc*1024 + cl*16;
            us8 hv = *(const us8*)(cp);
            us8 mv = *(const us8*)(cp + 32768);
            us8 lv = *(const us8*)(cp + 65536);
            float* dst = P32 + tloc*257 + kc*16 + hh2*8;
            #pragma unroll
            for (int j = 0; j < 8; ++j) dst[j] = rejoin(hv[j], mv[j], lv[j]);
        }
        __syncthreads();
        if (tid < 256) {               // mu partials: 8 threads per token
            int tk = tid >> 3, part = tid & 7;
            const float* pr = P32 + tk*257 + part*32;
            const float* wr = wsS + part*32;
            float s = 0.f;
            #pragma unroll
            for (int k = 0; k < 32; ++k) s += pr[k] * wr[k];
            muP[tk*8 + part] = s;
        }
        if (w >= 4) {                  // sumsq = V_G . patch (waves 4..7 hold G cols)
            int wv = w - 4;
            #pragma unroll
            for (int reg = 0; reg < 16; ++reg) {
                int row = (reg&3) + 8*(reg>>2) + 4*h;
                float sv = acc[mh][0][reg] * P32[row*257 + 64*wv + n31]
                         + acc[mh][1][reg] * P32[row*257 + 64*wv + 32 + n31];
                #pragma unroll
                for (int msk = 1; msk < 32; msk <<= 1) sv += __shfl_xor(sv, msk);
                if (n31 == 0) sqP[row*4 + wv] = sv;
            }
        }
        __syncthreads();
        if (tid < 32) {
            float pm = 0.f, sq = 0.f;
            #pragma unroll
            for (int p = 0; p < 8; ++p) pm += muP[tid*8 + p];
            #pragma unroll
            for (int v2 = 0; v2 < 4; ++v2) sq += sqP[tid*4 + v2];
            float m_ = pm * (1.f/512.f);
            float var = sq * (1.f/512.f) - m_*m_;
            lnMu[mh*32 + tid] = m_;
            lnRs[mh*32 + tid] = rsqrtf(var + 1e-5f);   // positive scale: argmax-neutral
        }
    }
    __syncthreads();   // publishes lnMu/lnRs; P32 dead

    // t = rs*(V - mu*p1), re-split into planes (waves 0..3 hold cols 0..255)
    if (w < 4) {
        #pragma unroll
        for (int mt = 0; mt < 2; ++mt)
            #pragma unroll
            for (int ntl = 0; ntl < 2; ++ntl) {
                int q = 32*(2*w + ntl) + n31;
                float p1v = p1S[q];
                #pragma unroll
                for (int reg = 0; reg < 16; ++reg) {
                    int row = (reg&3) + 8*(reg>>2) + 4*h;
                    int tk = 32*mt + row;
                    float tv = lnRs[tk] * (acc[mt][ntl][reg] - lnMu[tk]*p1v);
                    ushort_t hb, mb, lb; split3(tv, hb, mb, lb);
                    char* cp = smem + PL + mt*16384 + (q>>4)*1024
                             + (((q>>3)&1)*32 + row)*16 + (q&7)*2;
                    *(ushort_t*)cp = hb;
                    *(ushort_t*)(cp + 32768) = mb;
                    *(ushort_t*)(cp + 65536) = lb;
                }
            }
    }
    __syncthreads();   // publish t-planes (only barrier before GEMM2)

    // ================= GEMM2 + argmax: sim = t @ cbn^T, barrier-free =================
    float bestV[2][16]; int bestIx[2][16];
    #pragma unroll
    for (int mt = 0; mt < 2; ++mt)
        #pragma unroll
        for (int reg = 0; reg < 16; ++reg) { bestV[mt][reg] = -3.4e38f; bestIx[mt][reg] = 0; }

    loadB2(0, 0, bA);
    for (int sweep = 0; sweep < 2; ++sweep) {
        #pragma unroll
        for (int a = 0; a < 2; ++a)
            #pragma unroll
            for (int b2 = 0; b2 < 2; ++b2)
                #pragma unroll
                for (int r2 = 0; r2 < 16; ++r2) acc[a][b2][r2] = 0.f;

        for (int kc = 0; kc < 16; kc += 2) {
            bf16x8 a[3][2];
            loadB2(sweep, kc + 1, bB);
            loadA(kc, a);
            compute(a, bA);
            if (kc + 2 < 16) loadB2(sweep, kc + 2, bA);
            else if (sweep == 0) loadB2(1, 0, bA);
            loadA(kc + 1, a);
            compute(a, bB);
        }
        // fold sweep (ascending code, strict > : first-max tie-break)
        #pragma unroll
        for (int mt = 0; mt < 2; ++mt)
            #pragma unroll
            for (int ntl = 0; ntl < 2; ++ntl) {
                int codeBase = 512*sweep + 32*(2*w + ntl) + n31;
                #pragma unroll
                for (int reg = 0; reg < 16; ++reg) {
                    float v = acc[mt][ntl][reg];
                    if (v > bestV[mt][reg]) { bestV[mt][reg] = v; bestIx[mt][reg] = codeBase; }
                }
            }
    }

    // cross-lane (32 code-lanes) then cross-wave reduction, lowest-index-on-tie
    float* redV = (float*)(smem + RV);
    int*   redI = (int*)(smem + RI);
    #pragma unroll
    for (int mt = 0; mt < 2; ++mt)
        #pragma unroll
        for (int reg = 0; reg < 16; ++reg) {
            float bv = bestV[mt][reg]; int bi = bestIx[mt][reg];
            #pragma unroll
            for (int msk = 1; msk < 32; msk <<= 1) {
                float ov = __shfl_xor(bv, msk);
                int   oi = __shfl_xor(bi, msk);
                if (ov > bv || (ov == bv && oi < bi)) { bv = ov; bi = oi; }
            }
            if (n31 == 0) {
                int row = (reg&3) + 8*(reg>>2) + 4*h;
                int tk = 32*mt + row;
                redV[tk*8 + w] = bv;
                redI[tk*8 + w] = bi;
            }
        }
    __syncthreads();
    if (tid < 64) {
        float bv = redV[tid*8]; int bi = redI[tid*8];
        #pragma unroll
        for (int p = 1; p < 8; ++p) {
            float ov = redV[tid*8 + p]; int oi = redI[tid*8 + p];
            if (ov > bv || (ov == bv && oi < bi)) { bv = ov; bi = oi; }
        }
        out[n0 + tid] = bi;
    }
}

extern "C" void kernel_launch(void* const* d_in, const int* in_sizes, int n_in,
                              void* d_out, int out_size, void* d_ws, size_t ws_size,
                              hipStream_t stream) {
    const float* fbank = (const float*)d_in[0];   // 16 x 8192 x 128
    const float* convw = (const float*)d_in[1];   // [512][256]
    const float* proj  = (const float*)d_in[2];   // [512][256]
    const float* cbook = (const float*)d_in[3];   // [1024][256]
    int* out = (int*)d_out;                       // 65536 int32

    char* ws = (char*)d_ws;
    ushort_t* cbp = (ushort_t*)ws;                   // 1.5 MB code planes
    ushort_t* w2p = (ushort_t*)(ws + 0x180000);      // 768 KB weight planes
    float* wsum   = (float*)(ws + 0x240000);         // 1 KB
    float* p1     = (float*)(ws + 0x241000);         // 1 KB

    (void)hipFuncSetAttribute((const void*)k_mega,
                              hipFuncAttributeMaxDynamicSharedMemorySize, SMEM_TOTAL);

    hipLaunchKernelGGL(k_cbnorm, dim3(QN),  dim3(64),  0, stream, cbook, cbp);
    hipLaunchKernelGGL(k_prep,   dim3(514), dim3(256), 0, stream, convw, proj, w2p, wsum, p1);
    hipLaunchKernelGGL(k_mega,   dim3(NTOK/64), dim3(512), SMEM_TOTAL, stream,
                       fbank, w2p, cbp, wsum, p1, out);
}